// Round 1
// baseline (503.377 us; speedup 1.0000x reference)
//
#include <hip/hip_runtime.h>

// BCE-over-sparse-matches gather-reduce.
// B=8, N=M=2048 fixed by the problem; K derived from in_sizes[2].

static constexpr int   M_DIM   = 2048;
static constexpr long long PLANE = 2048LL * 2048LL;   // N*M elements per batch plane
static constexpr int   B_DIM   = 8;
static constexpr float LOG_CLAMP_F = -100.0f;

__global__ __launch_bounds__(256) void bce_gather_kernel(
    const float* __restrict__ pred,
    const float* __restrict__ gt,
    const int2*  __restrict__ matches,
    float*       __restrict__ out,
    int K, float inv_k)
{
    float acc = 0.0f;
    const int stride = gridDim.x * blockDim.x;
    for (int k = blockIdx.x * blockDim.x + threadIdx.x; k < K; k += stride) {
        const int2 rc = matches[k];                       // coalesced 8B/lane
        const long long base = (long long)rc.x * M_DIM + rc.y;

        // Issue all 16 independent gathers first (max MLP), compute after.
        float p[B_DIM], g[B_DIM];
        #pragma unroll
        for (int b = 0; b < B_DIM; ++b) {
            p[b] = pred[base + b * PLANE];
            g[b] = gt[base + b * PLANE];
        }
        #pragma unroll
        for (int b = 0; b < B_DIM; ++b) {
            const float lp  = fmaxf(logf(p[b]),    LOG_CLAMP_F);
            const float l1m = fmaxf(log1pf(-p[b]), LOG_CLAMP_F);
            acc -= g[b] * lp + (1.0f - g[b]) * l1m;
        }
    }

    // Wave-64 shuffle reduction
    #pragma unroll
    for (int off = 32; off > 0; off >>= 1)
        acc += __shfl_down(acc, off, 64);

    __shared__ float wsum[4];                             // 256 threads = 4 waves
    const int lane = threadIdx.x & 63;
    const int wid  = threadIdx.x >> 6;
    if (lane == 0) wsum[wid] = acc;
    __syncthreads();
    if (threadIdx.x == 0) {
        const float s = wsum[0] + wsum[1] + wsum[2] + wsum[3];
        atomicAdd(out, s * inv_k);                        // pre-scaled by 1/K
    }
}

extern "C" void kernel_launch(void* const* d_in, const int* in_sizes, int n_in,
                              void* d_out, int out_size, void* d_ws, size_t ws_size,
                              hipStream_t stream) {
    const float* pred    = (const float*)d_in[0];
    const float* gt      = (const float*)d_in[1];
    const int2*  matches = (const int2*)d_in[2];
    const int K = in_sizes[2] / 2;

    // d_out is re-poisoned to 0xAA before every timed launch — zero it.
    hipMemsetAsync(d_out, 0, sizeof(float), stream);

    const int block = 256;
    const int grid  = 4096;   // ~1.05M threads: ~1 match/thread, 16 blocks/CU
    bce_gather_kernel<<<grid, block, 0, stream>>>(
        pred, gt, matches, (float*)d_out, K, 1.0f / (float)K);
}

// Round 2
// 454.915 us; speedup vs baseline: 1.1065x; 1.1065x over previous
//
#include <hip/hip_runtime.h>

// BCE-over-sparse-matches gather-reduce, with row counting-sort for L2 locality.
// B=8, N=M=2048 fixed; K from in_sizes[2].

static constexpr int       N_ROWS      = 2048;
static constexpr int       M_DIM       = 2048;
static constexpr long long PLANE       = 2048LL * 2048LL;
static constexpr int       B_DIM       = 8;
static constexpr float     LOG_CLAMP_F = -100.0f;

// ---------- pass 1: row histogram ----------
__global__ __launch_bounds__(256) void hist_kernel(
    const int2* __restrict__ matches, unsigned* __restrict__ hist, int K)
{
    __shared__ unsigned lh[N_ROWS];
    for (int i = threadIdx.x; i < N_ROWS; i += 256) lh[i] = 0u;
    __syncthreads();
    const int stride = gridDim.x * blockDim.x;
    for (int k = blockIdx.x * blockDim.x + threadIdx.x; k < K; k += stride)
        atomicAdd(&lh[matches[k].x], 1u);
    __syncthreads();
    for (int i = threadIdx.x; i < N_ROWS; i += 256) {
        unsigned v = lh[i];
        if (v) atomicAdd(&hist[i], v);
    }
}

// ---------- pass 2: exclusive scan of 2048 bins (one block, 256 threads) ----------
__global__ __launch_bounds__(256) void scan_kernel(
    const unsigned* __restrict__ hist, unsigned* __restrict__ offsets)
{
    __shared__ unsigned wsums[4];
    const int t = threadIdx.x;
    unsigned v[8], s = 0;
    #pragma unroll
    for (int i = 0; i < 8; ++i) { v[i] = hist[t * 8 + i]; s += v[i]; }
    // inclusive wave scan of thread sums
    unsigned pre = s;
    #pragma unroll
    for (int off = 1; off < 64; off <<= 1) {
        unsigned n = __shfl_up(pre, off, 64);
        if ((t & 63) >= off) pre += n;
    }
    const unsigned excl = pre - s;
    if ((t & 63) == 63) wsums[t >> 6] = pre;
    __syncthreads();
    unsigned base = 0;
    for (int w = 0; w < (t >> 6); ++w) base += wsums[w];
    unsigned run = base + excl;
    #pragma unroll
    for (int i = 0; i < 8; ++i) { offsets[t * 8 + i] = run; run += v[i]; }
}

// ---------- pass 3: scatter matches into row-sorted order ----------
__global__ __launch_bounds__(256) void scatter_kernel(
    const int2* __restrict__ matches, unsigned* __restrict__ offsets,
    int2* __restrict__ sorted, int K)
{
    const int stride = gridDim.x * blockDim.x;
    for (int k = blockIdx.x * blockDim.x + threadIdx.x; k < K; k += stride) {
        const int2 rc = matches[k];
        const unsigned pos = atomicAdd(&offsets[rc.x], 1u);
        sorted[pos] = rc;
    }
}

// ---------- pass 4: main gather + BCE reduce ----------
__global__ __launch_bounds__(256) void bce_gather_kernel(
    const float* __restrict__ pred,
    const float* __restrict__ gt,
    const int2*  __restrict__ matches,
    float*       __restrict__ out,
    int K, float inv_k)
{
    float acc = 0.0f;
    const int stride = gridDim.x * blockDim.x;
    for (int k = blockIdx.x * blockDim.x + threadIdx.x; k < K; k += stride) {
        const int2 rc = matches[k];
        const long long base = (long long)rc.x * M_DIM + rc.y;
        float p[B_DIM], g[B_DIM];
        #pragma unroll
        for (int b = 0; b < B_DIM; ++b) {
            p[b] = pred[base + b * PLANE];
            g[b] = gt[base + b * PLANE];
        }
        #pragma unroll
        for (int b = 0; b < B_DIM; ++b) {
            const float lp  = fmaxf(logf(p[b]),    LOG_CLAMP_F);
            const float l1m = fmaxf(log1pf(-p[b]), LOG_CLAMP_F);
            acc -= g[b] * lp + (1.0f - g[b]) * l1m;
        }
    }
    #pragma unroll
    for (int off = 32; off > 0; off >>= 1)
        acc += __shfl_down(acc, off, 64);
    __shared__ float wsum[4];
    const int lane = threadIdx.x & 63;
    const int wid  = threadIdx.x >> 6;
    if (lane == 0) wsum[wid] = acc;
    __syncthreads();
    if (threadIdx.x == 0)
        atomicAdd(out, (wsum[0] + wsum[1] + wsum[2] + wsum[3]) * inv_k);
}

extern "C" void kernel_launch(void* const* d_in, const int* in_sizes, int n_in,
                              void* d_out, int out_size, void* d_ws, size_t ws_size,
                              hipStream_t stream) {
    const float* pred    = (const float*)d_in[0];
    const float* gt      = (const float*)d_in[1];
    const int2*  matches = (const int2*)d_in[2];
    const int K = in_sizes[2] / 2;

    hipMemsetAsync(d_out, 0, sizeof(float), stream);

    // workspace layout: [hist 2048 u32][offsets 2048 u32][sorted K int2]
    const size_t need = 2 * N_ROWS * sizeof(unsigned) + (size_t)K * sizeof(int2);

    if (ws_size >= need) {
        unsigned* hist    = (unsigned*)d_ws;
        unsigned* offsets = hist + N_ROWS;
        int2*     sorted  = (int2*)(offsets + N_ROWS);

        hipMemsetAsync(hist, 0, N_ROWS * sizeof(unsigned), stream);
        hist_kernel   <<<256,  256, 0, stream>>>(matches, hist, K);
        scan_kernel   <<<1,    256, 0, stream>>>(hist, offsets);
        scatter_kernel<<<1024, 256, 0, stream>>>(matches, offsets, sorted, K);
        bce_gather_kernel<<<4096, 256, 0, stream>>>(
            pred, gt, sorted, (float*)d_out, K, 1.0f / (float)K);
    } else {
        // fallback: unsorted direct gather
        bce_gather_kernel<<<4096, 256, 0, stream>>>(
            pred, gt, matches, (float*)d_out, K, 1.0f / (float)K);
    }
}

// Round 5
// 347.467 us; speedup vs baseline: 1.4487x; 1.3092x over previous
//
#include <hip/hip_runtime.h>

// BCE-over-sparse-matches, reformulated as count-weighted full-plane sweep.
// loss = (1/K) * sum_b sum_{r,c} count[r,c] * bce(pred[b,r,c], gt[b,r,c])
// B=8, N=M=2048 fixed; K from in_sizes[2].

static constexpr int       N_ROWS      = 2048;
static constexpr int       M_DIM       = 2048;
static constexpr long long PLANE       = 2048LL * 2048LL;   // 4,194,304
static constexpr int       B_DIM       = 8;
static constexpr float     LOG_CLAMP_F = -100.0f;

// ---------- pass 1: scatter counts (4M bins -> negligible contention) ----------
__global__ __launch_bounds__(256) void count_kernel(
    const int2* __restrict__ matches, unsigned* __restrict__ cnt, int K)
{
    const int stride = gridDim.x * blockDim.x;
    for (int k = blockIdx.x * blockDim.x + threadIdx.x; k < K; k += stride) {
        const int2 rc = matches[k];
        atomicAdd(&cnt[rc.x * M_DIM + rc.y], 1u);   // fire-and-forget
    }
}

// ---------- pass 2: streaming count-weighted BCE sweep ----------
__global__ __launch_bounds__(256) void bce_sweep_kernel(
    const float*    __restrict__ pred,
    const float*    __restrict__ gt,
    const unsigned* __restrict__ cnt,
    float*          __restrict__ out,
    float inv_k)
{
    float acc = 0.0f;
    const long long nChunks = PLANE / 4;           // float4 chunks per plane
    const long long stride  = (long long)gridDim.x * blockDim.x;

    for (long long c = (long long)blockIdx.x * blockDim.x + threadIdx.x;
         c < nChunks; c += stride) {
        const long long e = c * 4;
        const uint4 cc = *reinterpret_cast<const uint4*>(&cnt[e]);
        const float w0 = (float)cc.x, w1 = (float)cc.y,
                    w2 = (float)cc.z, w3 = (float)cc.w;

        #pragma unroll
        for (int b = 0; b < B_DIM; ++b) {
            const float4 p4 = *reinterpret_cast<const float4*>(&pred[b * PLANE + e]);
            const float4 g4 = *reinterpret_cast<const float4*>(&gt  [b * PLANE + e]);

            const float p[4] = {p4.x, p4.y, p4.z, p4.w};
            const float g[4] = {g4.x, g4.y, g4.z, g4.w};
            const float w[4] = {w0, w1, w2, w3};
            #pragma unroll
            for (int i = 0; i < 4; ++i) {
                const float lp  = fmaxf(logf(p[i]),    LOG_CLAMP_F);
                const float l1m = fmaxf(log1pf(-p[i]), LOG_CLAMP_F);
                acc -= w[i] * (g[i] * lp + (1.0f - g[i]) * l1m);
            }
        }
    }

    #pragma unroll
    for (int off = 32; off > 0; off >>= 1)
        acc += __shfl_down(acc, off, 64);
    __shared__ float wsum[4];
    const int lane = threadIdx.x & 63;
    const int wid  = threadIdx.x >> 6;
    if (lane == 0) wsum[wid] = acc;
    __syncthreads();
    if (threadIdx.x == 0)
        atomicAdd(out, (wsum[0] + wsum[1] + wsum[2] + wsum[3]) * inv_k);
}

// ---------- fallback: direct gather (ws too small) ----------
__global__ __launch_bounds__(256) void bce_gather_kernel(
    const float* __restrict__ pred,
    const float* __restrict__ gt,
    const int2*  __restrict__ matches,
    float*       __restrict__ out,
    int K, float inv_k)
{
    float acc = 0.0f;
    const int stride = gridDim.x * blockDim.x;
    for (int k = blockIdx.x * blockDim.x + threadIdx.x; k < K; k += stride) {
        const int2 rc = matches[k];
        const long long base = (long long)rc.x * M_DIM + rc.y;
        float p[B_DIM], g[B_DIM];
        #pragma unroll
        for (int b = 0; b < B_DIM; ++b) {
            p[b] = pred[base + b * PLANE];
            g[b] = gt[base + b * PLANE];
        }
        #pragma unroll
        for (int b = 0; b < B_DIM; ++b) {
            const float lp  = fmaxf(logf(p[b]),    LOG_CLAMP_F);
            const float l1m = fmaxf(log1pf(-p[b]), LOG_CLAMP_F);
            acc -= g[b] * lp + (1.0f - g[b]) * l1m;
        }
    }
    #pragma unroll
    for (int off = 32; off > 0; off >>= 1)
        acc += __shfl_down(acc, off, 64);
    __shared__ float wsum[4];
    const int lane = threadIdx.x & 63;
    const int wid  = threadIdx.x >> 6;
    if (lane == 0) wsum[wid] = acc;
    __syncthreads();
    if (threadIdx.x == 0)
        atomicAdd(out, (wsum[0] + wsum[1] + wsum[2] + wsum[3]) * inv_k);
}

extern "C" void kernel_launch(void* const* d_in, const int* in_sizes, int n_in,
                              void* d_out, int out_size, void* d_ws, size_t ws_size,
                              hipStream_t stream) {
    const float* pred    = (const float*)d_in[0];
    const float* gt      = (const float*)d_in[1];
    const int2*  matches = (const int2*)d_in[2];
    const int K = in_sizes[2] / 2;

    hipMemsetAsync(d_out, 0, sizeof(float), stream);

    const size_t need_counts = (size_t)PLANE * sizeof(unsigned);   // 16 MiB

    if (ws_size >= need_counts) {
        unsigned* cnt = (unsigned*)d_ws;
        hipMemsetAsync(cnt, 0, need_counts, stream);
        count_kernel<<<2048, 256, 0, stream>>>(matches, cnt, K);
        bce_sweep_kernel<<<2048, 256, 0, stream>>>(
            pred, gt, cnt, (float*)d_out, 1.0f / (float)K);
    } else {
        bce_gather_kernel<<<4096, 256, 0, stream>>>(
            pred, gt, matches, (float*)d_out, K, 1.0f / (float)K);
    }
}

// Round 6
// 309.131 us; speedup vs baseline: 1.6284x; 1.1240x over previous
//
#include <hip/hip_runtime.h>

// BCE-over-sparse-matches, as: dense per-cell BCE-sum precompute (streaming)
// + LLC-resident gather of the 1M matched cells.
// loss = (1/K) * sum_k S[r_k, c_k],  S[r,c] = sum_b bce(pred[b,r,c], gt[b,r,c])
// B=8, N=M=2048 fixed; K from in_sizes[2].

static constexpr int       M_DIM       = 2048;
static constexpr long long PLANE       = 2048LL * 2048LL;   // 4,194,304
static constexpr int       B_DIM       = 8;
static constexpr float     LOG_CLAMP_F = -100.0f;
static constexpr float     LN2F        = 0.69314718055994530942f;

// fast BCE term: hardware v_log_f32 (log2) * ln2; log2(0) = -inf clamps to -100
__device__ __forceinline__ float bce_term(float p, float g) {
    const float lp  = fmaxf(__log2f(p)        * LN2F, LOG_CLAMP_F);
    const float l1m = fmaxf(__log2f(1.0f - p) * LN2F, LOG_CLAMP_F);
    return -(g * (lp - l1m) + l1m);
}

// ---------- pass A: streaming per-cell BCE sum over the 8 planes ----------
__global__ __launch_bounds__(256) void bce_precompute_kernel(
    const float* __restrict__ pred,
    const float* __restrict__ gt,
    float*       __restrict__ S)
{
    const long long nChunks = PLANE / 4;            // float4 chunks
    const long long stride  = (long long)gridDim.x * blockDim.x;

    for (long long c = (long long)blockIdx.x * blockDim.x + threadIdx.x;
         c < nChunks; c += stride) {
        const long long e = c * 4;
        float s0 = 0.f, s1 = 0.f, s2 = 0.f, s3 = 0.f;
        #pragma unroll
        for (int b = 0; b < B_DIM; ++b) {
            const float4 p4 = *reinterpret_cast<const float4*>(&pred[b * PLANE + e]);
            const float4 g4 = *reinterpret_cast<const float4*>(&gt  [b * PLANE + e]);
            s0 += bce_term(p4.x, g4.x);
            s1 += bce_term(p4.y, g4.y);
            s2 += bce_term(p4.z, g4.z);
            s3 += bce_term(p4.w, g4.w);
        }
        *reinterpret_cast<float4*>(&S[e]) = make_float4(s0, s1, s2, s3);
    }
}

// ---------- pass B: gather S at the matches (LLC-hit) + reduce ----------
__global__ __launch_bounds__(256) void gather_sum_kernel(
    const float* __restrict__ S,
    const int2*  __restrict__ matches,
    float*       __restrict__ out,
    int K, float inv_k)
{
    float acc = 0.0f;
    const int T = gridDim.x * blockDim.x;
    int k = blockIdx.x * blockDim.x + threadIdx.x;

    // 4-deep batched gathers for MLP
    for (; k + 3 * T < K; k += 4 * T) {
        const int2 a = matches[k];
        const int2 b = matches[k + T];
        const int2 c = matches[k + 2 * T];
        const int2 d = matches[k + 3 * T];
        const float va = S[(long long)a.x * M_DIM + a.y];
        const float vb = S[(long long)b.x * M_DIM + b.y];
        const float vc = S[(long long)c.x * M_DIM + c.y];
        const float vd = S[(long long)d.x * M_DIM + d.y];
        acc += (va + vb) + (vc + vd);
    }
    for (; k < K; k += T)
        acc += S[(long long)matches[k].x * M_DIM + matches[k].y];

    #pragma unroll
    for (int off = 32; off > 0; off >>= 1)
        acc += __shfl_down(acc, off, 64);
    __shared__ float wsum[4];
    const int lane = threadIdx.x & 63;
    const int wid  = threadIdx.x >> 6;
    if (lane == 0) wsum[wid] = acc;
    __syncthreads();
    if (threadIdx.x == 0)
        atomicAdd(out, (wsum[0] + wsum[1] + wsum[2] + wsum[3]) * inv_k);
}

// ---------- fallback: direct gather (ws too small), fast logs ----------
__global__ __launch_bounds__(256) void bce_gather_kernel(
    const float* __restrict__ pred,
    const float* __restrict__ gt,
    const int2*  __restrict__ matches,
    float*       __restrict__ out,
    int K, float inv_k)
{
    float acc = 0.0f;
    const int stride = gridDim.x * blockDim.x;
    for (int k = blockIdx.x * blockDim.x + threadIdx.x; k < K; k += stride) {
        const int2 rc = matches[k];
        const long long base = (long long)rc.x * M_DIM + rc.y;
        float p[B_DIM], g[B_DIM];
        #pragma unroll
        for (int b = 0; b < B_DIM; ++b) {
            p[b] = pred[base + b * PLANE];
            g[b] = gt[base + b * PLANE];
        }
        #pragma unroll
        for (int b = 0; b < B_DIM; ++b)
            acc += bce_term(p[b], g[b]);
    }
    #pragma unroll
    for (int off = 32; off > 0; off >>= 1)
        acc += __shfl_down(acc, off, 64);
    __shared__ float wsum[4];
    const int lane = threadIdx.x & 63;
    const int wid  = threadIdx.x >> 6;
    if (lane == 0) wsum[wid] = acc;
    __syncthreads();
    if (threadIdx.x == 0)
        atomicAdd(out, (wsum[0] + wsum[1] + wsum[2] + wsum[3]) * inv_k);
}

extern "C" void kernel_launch(void* const* d_in, const int* in_sizes, int n_in,
                              void* d_out, int out_size, void* d_ws, size_t ws_size,
                              hipStream_t stream) {
    const float* pred    = (const float*)d_in[0];
    const float* gt      = (const float*)d_in[1];
    const int2*  matches = (const int2*)d_in[2];
    const int K = in_sizes[2] / 2;

    hipMemsetAsync(d_out, 0, sizeof(float), stream);

    const size_t need = (size_t)PLANE * sizeof(float);   // 16 MiB for S

    if (ws_size >= need) {
        float* S = (float*)d_ws;                         // fully overwritten, no memset
        bce_precompute_kernel<<<2048, 256, 0, stream>>>(pred, gt, S);
        gather_sum_kernel   <<<1024, 256, 0, stream>>>(
            S, matches, (float*)d_out, K, 1.0f / (float)K);
    } else {
        bce_gather_kernel<<<4096, 256, 0, stream>>>(
            pred, gt, matches, (float*)d_out, K, 1.0f / (float)K);
    }
}

// Round 14
// 282.685 us; speedup vs baseline: 1.7807x; 1.0936x over previous
//
#include <hip/hip_runtime.h>

// BCE-over-sparse-matches:
//   pass A: dense per-cell BCE-sum S[r,c] = sum_b bce(pred[b,r,c], gt[b,r,c])
//           (streaming, nontemporal input loads, 1 float4-chunk per thread)
//   pass B: gather S at the 1M matches -> per-block partials (no atomics)
//   pass C: single-block finalize -> out[0] = sum * 1/K
// B=8, N=M=2048 fixed; K from in_sizes[2].

static constexpr int       M_DIM       = 2048;
static constexpr long long PLANE       = 2048LL * 2048LL;   // 4,194,304
static constexpr int       B_DIM       = 8;
static constexpr float     LOG_CLAMP_F = -100.0f;
static constexpr float     LN2F        = 0.69314718055994530942f;
static constexpr int       GATHER_BLOCKS = 2048;

typedef float f32x4 __attribute__((ext_vector_type(4)));   // native vec for NT builtins

// fast BCE term: hardware v_log_f32 (log2) * ln2; log2(0) = -inf clamps to -100
__device__ __forceinline__ float bce_term(float p, float g) {
    const float lp  = fmaxf(__log2f(p)        * LN2F, LOG_CLAMP_F);
    const float l1m = fmaxf(__log2f(1.0f - p) * LN2F, LOG_CLAMP_F);
    return -(g * (lp - l1m) + l1m);
}

// ---------- pass A: 1 float4-chunk per thread, straight-line ----------
__global__ __launch_bounds__(256) void bce_precompute_kernel(
    const float* __restrict__ pred,
    const float* __restrict__ gt,
    float*       __restrict__ S)
{
    const long long c = (long long)blockIdx.x * blockDim.x + threadIdx.x;
    const long long e = c * 4;                       // grid covers PLANE/4 exactly
    float s0 = 0.f, s1 = 0.f, s2 = 0.f, s3 = 0.f;
    #pragma unroll
    for (int b = 0; b < B_DIM; ++b) {
        const f32x4 p4 = __builtin_nontemporal_load(
            reinterpret_cast<const f32x4*>(&pred[b * PLANE + e]));
        const f32x4 g4 = __builtin_nontemporal_load(
            reinterpret_cast<const f32x4*>(&gt[b * PLANE + e]));
        s0 += bce_term(p4.x, g4.x);
        s1 += bce_term(p4.y, g4.y);
        s2 += bce_term(p4.z, g4.z);
        s3 += bce_term(p4.w, g4.w);
    }
    f32x4 sv; sv.x = s0; sv.y = s1; sv.z = s2; sv.w = s3;
    *reinterpret_cast<f32x4*>(&S[e]) = sv;
}

// ---------- pass B: gather S at matches -> per-block partials ----------
__global__ __launch_bounds__(256) void gather_sum_kernel(
    const float* __restrict__ S,
    const int*   __restrict__ m,          // matches as raw int pairs
    float*       __restrict__ partials,
    int K)
{
    float acc = 0.0f;
    const int tid = blockIdx.x * blockDim.x + threadIdx.x;
    const int T   = gridDim.x * blockDim.x;

    const int KP = K >> 1;                // match-pairs via int4 loads
    const int4* m4 = reinterpret_cast<const int4*>(m);
    for (int i = tid; i < KP; i += T) {
        const int4 mm = m4[i];            // (r0,c0,r1,c1) coalesced 16B
        acc += S[mm.x * M_DIM + mm.y] + S[mm.z * M_DIM + mm.w];
    }
    for (int k = 2 * KP + tid; k < K; k += T)      // odd-K tail
        acc += S[m[2 * k] * M_DIM + m[2 * k + 1]];

    #pragma unroll
    for (int off = 32; off > 0; off >>= 1)
        acc += __shfl_down(acc, off, 64);
    __shared__ float wsum[4];
    const int lane = threadIdx.x & 63;
    const int wid  = threadIdx.x >> 6;
    if (lane == 0) wsum[wid] = acc;
    __syncthreads();
    if (threadIdx.x == 0)
        partials[blockIdx.x] = wsum[0] + wsum[1] + wsum[2] + wsum[3];
}

// ---------- pass C: finalize ----------
__global__ __launch_bounds__(256) void finalize_kernel(
    const float* __restrict__ partials, float* __restrict__ out,
    int n, float inv_k)
{
    float acc = 0.0f;
    for (int i = threadIdx.x; i < n; i += 256) acc += partials[i];
    #pragma unroll
    for (int off = 32; off > 0; off >>= 1)
        acc += __shfl_down(acc, off, 64);
    __shared__ float wsum[4];
    const int lane = threadIdx.x & 63;
    const int wid  = threadIdx.x >> 6;
    if (lane == 0) wsum[wid] = acc;
    __syncthreads();
    if (threadIdx.x == 0)
        out[0] = (wsum[0] + wsum[1] + wsum[2] + wsum[3]) * inv_k;
}

// ---------- fallback: direct gather (ws too small), fast logs ----------
__global__ __launch_bounds__(256) void bce_gather_kernel(
    const float* __restrict__ pred,
    const float* __restrict__ gt,
    const int2*  __restrict__ matches,
    float*       __restrict__ out,
    int K, float inv_k)
{
    float acc = 0.0f;
    const int stride = gridDim.x * blockDim.x;
    for (int k = blockIdx.x * blockDim.x + threadIdx.x; k < K; k += stride) {
        const int2 rc = matches[k];
        const long long base = (long long)rc.x * M_DIM + rc.y;
        float p[B_DIM], g[B_DIM];
        #pragma unroll
        for (int b = 0; b < B_DIM; ++b) {
            p[b] = pred[base + b * PLANE];
            g[b] = gt[base + b * PLANE];
        }
        #pragma unroll
        for (int b = 0; b < B_DIM; ++b)
            acc += bce_term(p[b], g[b]);
    }
    #pragma unroll
    for (int off = 32; off > 0; off >>= 1)
        acc += __shfl_down(acc, off, 64);
    __shared__ float wsum[4];
    const int lane = threadIdx.x & 63;
    const int wid  = threadIdx.x >> 6;
    if (lane == 0) wsum[wid] = acc;
    __syncthreads();
    if (threadIdx.x == 0)
        atomicAdd(out, (wsum[0] + wsum[1] + wsum[2] + wsum[3]) * inv_k);
}

extern "C" void kernel_launch(void* const* d_in, const int* in_sizes, int n_in,
                              void* d_out, int out_size, void* d_ws, size_t ws_size,
                              hipStream_t stream) {
    const float* pred    = (const float*)d_in[0];
    const float* gt      = (const float*)d_in[1];
    const int*   matches = (const int*)d_in[2];
    const int K = in_sizes[2] / 2;

    const size_t needS = (size_t)PLANE * sizeof(float);              // 16 MiB
    const size_t need  = needS + GATHER_BLOCKS * sizeof(float);

    if (ws_size >= need) {
        float* S        = (float*)d_ws;          // fully overwritten, no memset
        float* partials = (float*)((char*)d_ws + needS);

        bce_precompute_kernel<<<PLANE / 4 / 256, 256, 0, stream>>>(pred, gt, S);
        gather_sum_kernel<<<GATHER_BLOCKS, 256, 0, stream>>>(
            S, matches, partials, K);
        finalize_kernel<<<1, 256, 0, stream>>>(
            partials, (float*)d_out, GATHER_BLOCKS, 1.0f / (float)K);
    } else {
        (void)hipMemsetAsync(d_out, 0, sizeof(float), stream);
        bce_gather_kernel<<<4096, 256, 0, stream>>>(
            pred, gt, (const int2*)matches, (float*)d_out, K, 1.0f / (float)K);
    }
}